// Round 10
// baseline (69.215 us; speedup 1.0000x reference)
//
#include <hip/hip_runtime.h>
#include <hip/hip_bf16.h>
#include <math.h>

#define EPS_F 1e-7f

constexpr int Bn = 128, Sn = 1024, Dn = 256, ATTn = 128, QDn = 128;
constexpr int Mn = Bn * Sn;          // 131072 rows
constexpr int BM = 256;              // rows per block (16 waves x 16 rows)
constexpr int NBLK = Mn / BM;        // 512 blocks
constexpr int NJ = ATTn / 16;        // 8 column fragments

typedef short short8 __attribute__((ext_vector_type(8)));
typedef float f32x4  __attribute__((ext_vector_type(4)));

// Exact truncation split: f = hi + r exactly (hi = top-16-bit float),
// lo = bf16_rne(r). A_hi*B_hi + A_hi*B_lo + A_lo*B_hi ~ 2^-17 relative.
__device__ inline void split_bf(float f, ushort& hi, ushort& lo) {
    uint fb = __float_as_uint(f);
    hi = (ushort)(fb >> 16);
    float hf = __uint_as_float(fb & 0xffff0000u);
    float lf = f - hf;                       // exact
    __hip_bfloat16 lb = __float2bfloat16(lf);
    __builtin_memcpy(&lo, &lb, 2);
}

__device__ inline float tanh_fast(float x) {
    float cx = fminf(9.0f, fmaxf(-9.0f, x));
    float e = __builtin_amdgcn_exp2f(cx * 2.8853900817779268f);  // e^{2x}
    return (e - 1.0f) * __builtin_amdgcn_rcpf(e + 1.0f);
}

// async global->LDS, 16B per lane. LDS dest is wave-uniform base + lane*16.
__device__ inline void gload_lds16(const void* g, void* lds_base) {
    __builtin_amdgcn_global_load_lds(
        (const __attribute__((address_space(1))) unsigned int*)g,
        (__attribute__((address_space(3))) unsigned int*)lds_base, 16, 0, 0);
}

#define MFMA_BF16 __builtin_amdgcn_mfma_f32_16x16x32_bf16

// ---------------- ws layout (bytes) ----------------
// [0,512)              u (128 f32)
// [512,66048)          Bhi (4096 chunks x 8 bf16)
// [66048,131584)       Blo
// [131584,655872)      P   (512 blk * 256 d f32)
// [655872,657920)      den (512 f32)

// Merged prep: block 0 computes u = W_u @ query; blocks 1..16 build the
// MFMA-B-fragment-ordered bf16 hi/lo copies of W.
// Fragment (ks,j): lane l holds col = 16j+(l&15), k = 32ks+(l>>4)*8+i.
__global__ __launch_bounds__(256) void k_prep(
    const float* __restrict__ Wu, const float* __restrict__ q,
    float* __restrict__ u,
    const float* __restrict__ W,
    ushort* __restrict__ Bhi, ushort* __restrict__ Blo)
{
    if (blockIdx.x == 0) {
        __shared__ float qs[QDn];
        int t = threadIdx.x;
        if (t < QDn) qs[t] = q[t];
        __syncthreads();
        if (t < ATTn) {
            float acc = 0.f;
            #pragma unroll 8
            for (int j = 0; j < QDn; ++j) acc += Wu[t * QDn + j] * qs[j];
            u[t] = acc;
        }
        return;
    }
    int gid  = (blockIdx.x - 1) * 256 + threadIdx.x;   // 0..4095
    int lane = gid & 63;
    int j    = (gid >> 6) & 7;
    int ks   = gid >> 9;
    int col  = j * 16 + (lane & 15);
    int kb   = ks * 32 + (lane >> 4) * 8;
    #pragma unroll
    for (int i = 0; i < 8; ++i) {
        float f = W[(size_t)(kb + i) * ATTn + col];
        ushort h, l;
        split_bf(f, h, l);
        size_t idx = (size_t)gid * 8 + i;
        Bhi[idx] = h; Blo[idx] = l;
    }
}

// One k-step (K=32): convert kv -> bf16 hi/lo, refill kv ring 4 ahead,
// 8 column fragments x 3 split-MFMAs with j+1 LDS prefetch.
template<int KS>
__device__ __forceinline__ void kstep(
    const float4* smem, const float* kb,
    float4 (&kv)[4][2], f32x4 (&acc)[NJ], int lane)
{
    constexpr int S = KS & 3;
    short8 ah, al;
    {
        float4 v0 = kv[S][0], v1 = kv[S][1];
        float f[8] = {v0.x, v0.y, v0.z, v0.w, v1.x, v1.y, v1.z, v1.w};
        #pragma unroll
        for (int i = 0; i < 8; ++i) {
            ushort h, l;
            split_bf(f[i], h, l);
            ah[i] = (short)h; al[i] = (short)l;
        }
    }
    if (KS + 4 < 8) {   // 4-deep counted-vmcnt prefetch
        kv[S][0] = *(const float4*)(kb + (KS + 4) * 32);
        kv[S][1] = *(const float4*)(kb + (KS + 4) * 32 + 4);
    }
    const float4* Bh = smem + KS * 512 + lane;
    const float4* Bl = smem + 4096 + KS * 512 + lane;
    short8 bh = *(const short8*)Bh;
    short8 bl = *(const short8*)Bl;
    #pragma unroll
    for (int j = 0; j < NJ; ++j) {
        short8 nbh, nbl;
        if (j + 1 < NJ) {
            nbh = *(const short8*)(Bh + (j + 1) * 64);
            nbl = *(const short8*)(Bl + (j + 1) * 64);
        }
        acc[j] = MFMA_BF16(ah, bh, acc[j], 0, 0, 0);
        acc[j] = MFMA_BF16(ah, bl, acc[j], 0, 0, 0);
        acc[j] = MFMA_BF16(al, bh, acc[j], 0, 0, 0);
        bh = nbh; bl = nbl;
    }
}

// Fused: scores (bf16-split MFMA, K=256, N=128) + partial weighted sums.
// 16 waves x 16 rows (BM=256); FULL B (hi+lo, 128 KB) staged to LDS once;
// the whole 8-k-step loop then runs with ZERO barriers.
__global__ __launch_bounds__(1024) void k_scores(
    const float*  __restrict__ key,
    const ushort* __restrict__ Bhi, const ushort* __restrict__ Blo,
    const float*  __restrict__ bias, const float* __restrict__ u,
    const int*    __restrict__ mask,
    float* __restrict__ P, float* __restrict__ den)
{
    __shared__ float4 smem[8192];        // 128 KB: full B; aliased es/part after
    float*  esp   = (float*)smem;        // [256] scores (B dead by then)
    float4* partp = smem + 64;           // [16][64] float4 partials

    const int t    = threadIdx.x;        // 0..1023
    const int lane = t & 63;
    const int w    = t >> 6;             // wave 0..15 -> rows w*16..w*16+15
    const int gb   = blockIdx.x;
    const int row0 = gb * BM;
    const int l15  = lane & 15;
    const int lg   = lane >> 4;

    const float* kb = key + (size_t)(row0 + w * 16 + l15) * Dn + lg * 8;

    f32x4 acc[NJ];
    #pragma unroll
    for (int j = 0; j < NJ; ++j) acc[j] = (f32x4){0.f, 0.f, 0.f, 0.f};

    // kv ring: k-steps 0..3
    float4 kv[4][2];
    #pragma unroll
    for (int s = 0; s < 4; ++s) {
        kv[s][0] = *(const float4*)(kb + s * 32);
        kv[s][1] = *(const float4*)(kb + s * 32 + 4);
    }

    // stage full B (hi: slots 0..4095, lo: 4096..8191), linear
    #pragma unroll
    for (int i = 0; i < 8; ++i) {
        int c  = i * 1024 + t;           // 0..8191
        int hp = c >> 12;                // wave-uniform
        int c2 = c & 4095;
        const ushort* src = (hp ? Blo : Bhi) + (size_t)c2 * 8;
        gload_lds16(src, smem + (i * 1024 + w * 64));
    }
    __syncthreads();

    kstep<0>(smem, kb, kv, acc, lane);
    kstep<1>(smem, kb, kv, acc, lane);
    kstep<2>(smem, kb, kv, acc, lane);
    kstep<3>(smem, kb, kv, acc, lane);
    kstep<4>(smem, kb, kv, acc, lane);
    kstep<5>(smem, kb, kv, acc, lane);
    kstep<6>(smem, kb, kv, acc, lane);
    kstep<7>(smem, kb, kv, acc, lane);
    __syncthreads();                     // B dead; smem reusable

    // Epilogue: s(row) = sum_col tanh(acc+bias)*u; e = exp(s)*mask.
    // C/D layout: col = 16j + l15, row(frag-local) = lg*4 + reg.
    float s4[4] = {0.f, 0.f, 0.f, 0.f};
    #pragma unroll
    for (int j = 0; j < NJ; ++j) {
        int col = j * 16 + l15;
        float bv = bias[col], uvv = u[col];
        #pragma unroll
        for (int reg = 0; reg < 4; ++reg)
            s4[reg] += tanh_fast(acc[j][reg] + bv) * uvv;
    }
    #pragma unroll
    for (int reg = 0; reg < 4; ++reg) {
        float s = s4[reg];
        s += __shfl_xor(s, 1);
        s += __shfl_xor(s, 2);
        s += __shfl_xor(s, 4);
        s += __shfl_xor(s, 8);
        if (l15 == 0) {
            int rl = w * 16 + lg * 4 + reg;
            esp[rl] = __builtin_amdgcn_exp2f(s * 1.4426950408889634f)
                      * (float)mask[row0 + rl];
        }
    }
    __syncthreads();

    // block-partial denominator (256 scores)
    if (t < 64) {
        float v = esp[t] + esp[t + 64] + esp[t + 128] + esp[t + 192];
        #pragma unroll
        for (int m = 1; m < 64; m <<= 1) v += __shfl_xor(v, m);
        if (t == 0) den[gb] = v;
    }

    // phase 2: wave w sums its 16 rows over all d (tile is L2/L3-hot).
    {
        const float4* kt = (const float4*)(key + (size_t)(row0 + w * 16) * Dn);
        float4 a2 = make_float4(0.f, 0.f, 0.f, 0.f);
        #pragma unroll 4
        for (int s2 = 0; s2 < 16; ++s2) {
            float wv   = esp[w * 16 + s2];
            float4 kvv = kt[(size_t)s2 * 64 + lane];
            a2.x += wv * kvv.x; a2.y += wv * kvv.y;
            a2.z += wv * kvv.z; a2.w += wv * kvv.w;
        }
        partp[w * 64 + lane] = a2;
    }
    __syncthreads();

    if (t < 64) {
        float4 o = partp[t];
        #pragma unroll
        for (int wv = 1; wv < 16; ++wv) {
            float4 p = partp[wv * 64 + t];
            o.x += p.x; o.y += p.y; o.z += p.z; o.w += p.w;
        }
        *(float4*)(P + (size_t)gb * Dn + t * 4) = o;
    }
}

// combine 4 block-partials per batch, normalize.
__global__ __launch_bounds__(256) void k_final(const float* __restrict__ P,
        const float* __restrict__ den, float* __restrict__ out) {
    int b = blockIdx.x, t = threadIdx.x;
    float dtot = 0.f;
    #pragma unroll
    for (int k = 0; k < 4; ++k) dtot += den[b * 4 + k];
    float o = 0.f;
    #pragma unroll
    for (int k = 0; k < 4; ++k) o += P[(size_t)(b * 4 + k) * Dn + t];
    out[(size_t)b * Dn + t] = o / (dtot + EPS_F);
}

extern "C" void kernel_launch(void* const* d_in, const int* in_sizes, int n_in,
                              void* d_out, int out_size, void* d_ws, size_t ws_size,
                              hipStream_t stream) {
    const float* key   = (const float*)d_in[0];
    const float* query = (const float*)d_in[1];
    const int*   mask  = (const int*)d_in[2];
    const float* W     = (const float*)d_in[3];
    const float* bias  = (const float*)d_in[4];
    const float* Wu    = (const float*)d_in[5];
    float* out = (float*)d_out;

    char* ws = (char*)d_ws;
    float*  u   = (float*)(ws);
    ushort* Bhi = (ushort*)(ws + 512);
    ushort* Blo = (ushort*)(ws + 66048);
    float*  Pp  = (float*)(ws + 131584);
    float*  den = (float*)(ws + 655872);

    hipLaunchKernelGGL(k_prep,   dim3(17),   dim3(256),  0, stream, Wu, query, u, W, Bhi, Blo);
    hipLaunchKernelGGL(k_scores, dim3(NBLK), dim3(1024), 0, stream,
                       key, Bhi, Blo, bias, u, mask, Pp, den);
    hipLaunchKernelGGL(k_final,  dim3(Bn),   dim3(256),  0, stream, Pp, den, out);
}